// Round 3
// baseline (305.467 us; speedup 1.0000x reference)
//
#include <hip/hip_runtime.h>
#include <stdint.h>

// NeiAttention: B=512, N=32, S=16, EF=64, NF=D=128, K=192
// v5: v stays in REGISTERS (no lds_v round-trip). 512 thr / 8 waves,
//     wave-per-col-tile, 2 (b,n) tiles per iteration.
//     alpha: per-lane x[c]*acc products, shfl over l15, tiny LDS partial
//     reduce; softmax+weighted sum fully from acc regs + shfl over quads.
//     Prefetch restored; launch_bounds(512,6) -> 85-reg cap, no spill
//     (live set ~78). LDS 30KB -> 13KB. 3 barriers/iter over 2 tiles.

typedef __attribute__((ext_vector_type(8))) short short8;
typedef __attribute__((ext_vector_type(4))) float float4_t;
typedef __attribute__((ext_vector_type(4))) unsigned short ushort4_t;

#define GRID_ 2048
#define ITERS_ 4   // 2048 blocks * 4 iters * 2 tiles = 16384 = B*N

__device__ __forceinline__ unsigned short f2bf(float f) {
    uint32_t u = __float_as_uint(f);
    u += 0x7fffu + ((u >> 16) & 1u);   // RNE
    return (unsigned short)(u >> 16);
}

// Swizzled A-frag LDS offset (ushort units) for element (s, k):
// owner slot X = (k/32)*64 + ((k%32)/8)*16 + s; low 3 bits of X XORed with
// a hash of the high bits -> staging writes spread across banks; fragment
// reads apply the identical swizzle (slot = q*64 + (lx^q)). Verified R2.
__device__ __forceinline__ int aoff(int s, int kc) {
    int X = ((kc >> 5) << 6) + (((kc & 31) >> 3) << 4) + s;
    X ^= ((X >> 3) ^ (X >> 6)) & 7;
    return X * 8 + (kc & 7);
}

__global__ __launch_bounds__(512, 6) void nei_attn_kernel(
    const float* __restrict__ x,
    const float* __restrict__ rel,
    const float* __restrict__ node,
    const float* __restrict__ W,
    const float* __restrict__ bias,
    float* __restrict__ out)
{
    __shared__ __align__(16) unsigned short lds_a[2][3072]; // 12 KB bf16 A-frags
    __shared__ __align__(16) float lds_ap[2][8][16];        // per-wave alpha partials
    __shared__ __align__(16) float lds_alpha[2][16];

    const int t    = threadIdx.x;
    const int tl   = t & 255;       // thread within half
    const int h    = t >> 8;        // staging half = tile within iteration
    const int lane = t & 63;
    const int wv   = t >> 6;        // wave 0..7 = output column tile
    const int l15  = lane & 15;
    const int quad = (lane >> 4) & 3;
    const int colw = wv * 16 + l15; // this lane's output column

    // ---- W^T B-fragments + bias: wave wv owns cols wv*16..wv*16+15 ----
    short8 bf[6];
    const float bias_c = bias[colw];
    #pragma unroll
    for (int q = 0; q < 6; ++q) {
        const float* p = W + colw * 192 + q * 32 + quad * 8;
        float4_t a0 = *(const float4_t*)p;
        float4_t a1 = *(const float4_t*)(p + 4);
        short8 f;
        f[0] = (short)f2bf(a0.x); f[1] = (short)f2bf(a0.y);
        f[2] = (short)f2bf(a0.z); f[3] = (short)f2bf(a0.w);
        f[4] = (short)f2bf(a1.x); f[5] = (short)f2bf(a1.y);
        f[6] = (short)f2bf(a1.z); f[7] = (short)f2bf(a1.w);
        bf[q] = f;
    }

    // Staging map per half (768 float4 per tile over 256 threads, 3 each)
    const int s0 = tl >> 4,  kc0 = (tl & 15) << 2;
    const int s1 = tl >> 5,  kc1 = 64 + ((tl & 31) << 2);
    const int s2 = s1 + 8;
    const int ao0 = h * 3072 + aoff(s0, kc0);
    const int ao1 = h * 3072 + aoff(s1, kc1);
    const int ao2 = h * 3072 + aoff(s2, kc1);
    const int lx = lane ^ ((lane >> 3) & 7);   // read-side swizzle base
    unsigned short* la = &lds_a[0][0];

    int idx = blockIdx.x * (ITERS_ * 2);

    // ---- prefetch iteration 0 ----
    float4_t pf0, pf1, pf2;
    float px0, px1;
    {
        const float* pr = rel  + (idx + h) * 1024;
        const float* pn = node + (idx + h) * 2048;
        pf0 = *(const float4_t*)(pr + tl * 4);
        pf1 = *(const float4_t*)(pn + tl * 4);
        pf2 = *(const float4_t*)(pn + 1024 + tl * 4);
        px0 = x[idx * 128 + colw];
        px1 = x[(idx + 1) * 128 + colw];
    }

    #pragma unroll 1
    for (int it = 0; it < ITERS_; ++it) {
        // ---- stage regs -> LDS (bf16, swizzled A-fragment layout) ----
        {
            ushort4_t u;
            u[0] = f2bf(pf0.x); u[1] = f2bf(pf0.y); u[2] = f2bf(pf0.z); u[3] = f2bf(pf0.w);
            *(ushort4_t*)&la[ao0] = u;
            u[0] = f2bf(pf1.x); u[1] = f2bf(pf1.y); u[2] = f2bf(pf1.z); u[3] = f2bf(pf1.w);
            *(ushort4_t*)&la[ao1] = u;
            u[0] = f2bf(pf2.x); u[1] = f2bf(pf2.y); u[2] = f2bf(pf2.z); u[3] = f2bf(pf2.w);
            *(ushort4_t*)&la[ao2] = u;
        }
        __syncthreads();   // (1) lds_a ready

        const float cx0 = px0, cx1 = px1;   // this iter's x values

        // ---- prefetch next iteration (hidden under MFMA + epilogue) ----
        if (it + 1 < ITERS_) {
            const int nidx = idx + 2;
            const float* pr = rel  + (nidx + h) * 1024;
            const float* pn = node + (nidx + h) * 2048;
            pf0 = *(const float4_t*)(pr + tl * 4);
            pf1 = *(const float4_t*)(pn + tl * 4);
            pf2 = *(const float4_t*)(pn + 1024 + tl * 4);
            px0 = x[nidx * 128 + colw];
            px1 = x[(nidx + 1) * 128 + colw];
        }

        // ---- projection: wave wv computes its 16 cols for BOTH tiles ----
        float4_t acc0 = {0.f, 0.f, 0.f, 0.f};
        float4_t acc1 = {0.f, 0.f, 0.f, 0.f};
        #pragma unroll
        for (int q = 0; q < 6; ++q) {
            short8 af0 = *(const short8*)&la[(q * 64 + (lx ^ q)) * 8];
            short8 af1 = *(const short8*)&la[3072 + (q * 64 + (lx ^ q)) * 8];
            acc0 = __builtin_amdgcn_mfma_f32_16x16x32_bf16(af0, bf[q], acc0, 0, 0, 0);
            acc1 = __builtin_amdgcn_mfma_f32_16x16x32_bf16(af1, bf[q], acc1, 0, 0, 0);
        }
        // lane holds v[quad*4+r][colw] (+bias)
        #pragma unroll
        for (int r = 0; r < 4; ++r) { acc0[r] += bias_c; acc1[r] += bias_c; }

        // ---- alpha partials: x[c]*v[s][c], reduce 16 cols via shfl(l15) ----
        float4_t pr0, pr1;
        #pragma unroll
        for (int r = 0; r < 4; ++r) { pr0[r] = cx0 * acc0[r]; pr1[r] = cx1 * acc1[r]; }
        #pragma unroll
        for (int msk = 1; msk <= 8; msk <<= 1) {
            #pragma unroll
            for (int r = 0; r < 4; ++r) {
                pr0[r] += __shfl_xor(pr0[r], msk);
                pr1[r] += __shfl_xor(pr1[r], msk);
            }
        }
        if (l15 == 0) {   // lane quad*16: partials for s = quad*4+0..3
            *(float4_t*)&lds_ap[0][wv][quad << 2] = pr0;
            *(float4_t*)&lds_ap[1][wv][quad << 2] = pr1;
        }
        __syncthreads();   // (2) partials ready

        if (t < 32) {      // (tile, s) = (t>>4, t&15): sum 8 wave-partials
            const int ht = t >> 4, s = t & 15;
            float a = 0.f;
            #pragma unroll
            for (int w = 0; w < 8; ++w) a += lds_ap[ht][w][s];
            lds_alpha[ht][s] = a * 0.08838834764831845f;   // 1/sqrt(128)
        }
        __syncthreads();   // (3) alphas ready

        // ---- softmax + weighted sum from registers (per tile) ----
        #define SOFTMAX_TILE(AL, ACC, TIDX)                                         \
        {                                                                           \
            const float* al = (AL);                                                 \
            float4_t a0 = *(const float4_t*)&al[0];                                 \
            float4_t a1 = *(const float4_t*)&al[4];                                 \
            float4_t a2 = *(const float4_t*)&al[8];                                 \
            float4_t a3 = *(const float4_t*)&al[12];                                \
            float4_t er = *(const float4_t*)&al[quad << 2];                         \
            float mx = fmaxf(fmaxf(fmaxf(a0[0], a0[1]), fmaxf(a0[2], a0[3])),       \
                             fmaxf(fmaxf(a1[0], a1[1]), fmaxf(a1[2], a1[3])));      \
            mx = fmaxf(mx, fmaxf(fmaxf(fmaxf(a2[0], a2[1]), fmaxf(a2[2], a2[3])),   \
                                 fmaxf(fmaxf(a3[0], a3[1]), fmaxf(a3[2], a3[3])))); \
            float den = 0.f;                                                        \
            _Pragma("unroll") for (int j = 0; j < 4; ++j) den += __expf(a0[j] - mx);\
            _Pragma("unroll") for (int j = 0; j < 4; ++j) den += __expf(a1[j] - mx);\
            _Pragma("unroll") for (int j = 0; j < 4; ++j) den += __expf(a2[j] - mx);\
            _Pragma("unroll") for (int j = 0; j < 4; ++j) den += __expf(a3[j] - mx);\
            float p = 0.f;                                                          \
            _Pragma("unroll") for (int r = 0; r < 4; ++r)                           \
                p += __expf(er[r] - mx) * (ACC)[r];                                 \
            p += __shfl_xor(p, 16);                                                 \
            p += __shfl_xor(p, 32);                                                 \
            if (quad == 0) out[(TIDX) * 128 + colw] = p / den;                      \
        }

        SOFTMAX_TILE(lds_alpha[0], acc0, idx)
        SOFTMAX_TILE(lds_alpha[1], acc1, idx + 1)
        #undef SOFTMAX_TILE

        idx += 2;
        // no trailing barrier: next-iter staging writes only lds_a, whose
        // readers (MFMA phase) all retired before barrier (2) of this iter;
        // staging happens after barrier (3) on every thread.
    }
}

extern "C" void kernel_launch(void* const* d_in, const int* in_sizes, int n_in,
                              void* d_out, int out_size, void* d_ws, size_t ws_size,
                              hipStream_t stream) {
    const float* x    = (const float*)d_in[0];
    const float* rel  = (const float*)d_in[1];
    const float* node = (const float*)d_in[2];
    const float* W    = (const float*)d_in[3];
    const float* bias = (const float*)d_in[4];
    float* out = (float*)d_out;
    hipLaunchKernelGGL(nei_attn_kernel, dim3(GRID_), dim3(512), 0, stream,
                       x, rel, node, W, bias, out);
}